// Round 6
// baseline (528.563 us; speedup 1.0000x reference)
//
#include <hip/hip_runtime.h>
#include <cstdint>

#define KDIM 4096
#define NNODE 4096
#define KSPLIT 2
#define KHALF (KDIM / KSPLIT)

typedef __bf16 bf16x8 __attribute__((ext_vector_type(8)));
typedef float floatx4 __attribute__((ext_vector_type(4)));

__device__ __forceinline__ uint16_t f2b(float f) {
  union { float f; uint32_t u; } v; v.f = f;
  uint32_t u = v.u;
  return (uint16_t)((u + 0x7FFFu + ((u >> 16) & 1u)) >> 16);  // RNE
}
__device__ __forceinline__ float b2f(uint16_t h) {
  union { uint32_t u; float f; } v; v.u = ((uint32_t)h) << 16; return v.f;
}

// ---------- fp32 -> bf16 conversion of both supports ----------
__global__ __launch_bounds__(256) void cvt_supports(
    const float* __restrict__ s0, const float* __restrict__ s1,
    uint16_t* __restrict__ d0, uint16_t* __restrict__ d1) {
  const float* src = blockIdx.y ? s1 : s0;
  uint16_t* dst = blockIdx.y ? d1 : d0;
  size_t i = ((size_t)blockIdx.x * 256 + threadIdx.x) * 4;
  float4 v = *(const float4*)(src + i);
  ushort4 o;
  o.x = f2b(v.x); o.y = f2b(v.y); o.z = f2b(v.z); o.w = f2b(v.w);
  *(ushort4*)(dst + i) = o;
}

// ---------- pack A-operand for GEMM1: rows = (b, [feats(2); prev(16)]) ----------
__global__ __launch_bounds__(256) void pack_x1(
    const float* __restrict__ inp, const float* __restrict__ st,
    uint16_t* __restrict__ X1) {
  size_t e = ((size_t)blockIdx.x * 256 + threadIdx.x) * 4;  // elem in (1152,4096)
  int r = (int)(e >> 12), n = (int)(e & 4095);
  int b = r / 18, c = r - b * 18;
  const float* src = (c < 2) ? (inp + (size_t)b * 8192 + (size_t)c * 4096 + n)
                             : (st + (size_t)b * 65536 + (size_t)(c - 2) * 4096 + n);
  float4 v = *(const float4*)src;
  ushort4 o;
  o.x = f2b(v.x); o.y = f2b(v.y); o.z = f2b(v.z); o.w = f2b(v.w);
  *(ushort4*)(X1 + e) = o;
}

// ---------- bf16 GEMM: C = A * S^T, split-K=2, S row-major.
// 128x128 tile, BK=32, 4 waves 2x2, 16x16x32 MFMA.
// R5 post-mortem: depth-1 double-buffer gave 0 — slack (1 step ~350 cyc) <
// LLC load latency (~700-900 cyc; supports live in LLC, L2/XCD only 4MB).
// R6: (a) depth-3 pipeline, 4 LDS buffers; tile k+3 issued at step k, waited
// at step k+3 via vmcnt(8) (2 tiles stay in flight — AITER discipline);
// (b) XCD-aware block decode: bid&7 = XCD, blocks on one XCD iterate all
// row-tiles for a fixed (col-stripe, support) so each 1MB S-stripe is
// L2-resident and reused 9x/8x.
#define GLL(gptr, lptr)                                                        \
  __builtin_amdgcn_global_load_lds(                                            \
      (const __attribute__((address_space(1))) uint32_t*)(gptr),               \
      (__attribute__((address_space(3))) uint32_t*)(lptr), 16, 0, 0)

#define STEP(VMIMM, K0)                                                        \
  do {                                                                         \
    const int _t = ((K0) - kBeg) >> 5;                                         \
    const int _p = _t & 3;                                                     \
    __builtin_amdgcn_s_waitcnt(VMIMM);                                         \
    __builtin_amdgcn_s_barrier();                                              \
    if ((K0) + 96 < kEnd) {                                                    \
      const int _nb = (_t + 3) & 3;                                            \
      GLL(gA[0] + (K0) + 96, &lsA[_nb][0] + ldsOff[0]);                        \
      GLL(gB[0] + (K0) + 96, &lsB[_nb][0] + ldsOff[0]);                        \
      GLL(gA[1] + (K0) + 96, &lsA[_nb][0] + ldsOff[1]);                        \
      GLL(gB[1] + (K0) + 96, &lsB[_nb][0] + ldsOff[1]);                        \
    }                                                                          \
    bf16x8 af[4], bfr[4];                                                      \
    _Pragma("unroll") for (int rt = 0; rt < 4; ++rt)                           \
        af[rt] = *(const bf16x8*)(&lsA[_p][0] +                                \
                                  (q * 128 + wr * 64 + rt * 16 + mr) * 8);     \
    _Pragma("unroll") for (int ct = 0; ct < 4; ++ct)                           \
        bfr[ct] = *(const bf16x8*)(&lsB[_p][0] +                               \
                                   (q * 128 + wc * 64 + ct * 16 + mr) * 8);    \
    _Pragma("unroll") for (int rt = 0; rt < 4; ++rt)                           \
        _Pragma("unroll") for (int ct = 0; ct < 4; ++ct)                       \
            acc[rt][ct] = __builtin_amdgcn_mfma_f32_16x16x32_bf16(             \
                af[rt], bfr[ct], acc[rt][ct], 0, 0, 0);                        \
  } while (0)

template <int MODE>
__global__ __launch_bounds__(256) void gemm_bt(
    const uint16_t* __restrict__ A, const uint16_t* __restrict__ S0,
    const uint16_t* __restrict__ S1, uint16_t* __restrict__ D) {
  constexpr int CPB = (MODE == 1) ? 18 : 16;    // A channels per batch
  constexpr int OUTC = (MODE == 1) ? 36 : 32;   // output channels per batch
  constexpr int YT = (MODE == 1) ? 9 : 8;       // row tiles
  constexpr size_t PSTRIDE = (size_t)64 * OUTC * NNODE;  // partial-buffer stride
  __shared__ __align__(16) uint16_t lsA[4][128 * 32];
  __shared__ __align__(16) uint16_t lsB[4][128 * 32];
  const int tid = threadIdx.x;
  const int lane = tid & 63, wave = tid >> 6;
  const int wr = wave >> 1, wc = wave & 1;

  // XCD-aware decode: xcd = bid&7 (dispatch round-robin heuristic; speed-only).
  // Within an XCD, y varies fastest for a fixed (x-stripe, z) so the S-stripe
  // (1 MB) stays hot in that XCD's 4 MB L2 for YT consecutive blocks.
  const int bid = blockIdx.x;
  const int xcd = bid & 7, lid = bid >> 3;
  const int g = lid / YT, y = lid - g * YT;
  const int combo = g * 8 + xcd;
  const int x = combo & 31, z = combo >> 5;
  const int s = z & 1, ks = z >> 1;
  const uint16_t* __restrict__ Bm = s ? S1 : S0;
  const int rowBase = y * 128;
  const int colBase = x * 128;

  // staging: 512 slots of 16B per tile; wave handles 2 issues of 64 slots each
  const uint16_t* gA[2];
  const uint16_t* gB[2];
  uint32_t ldsOff[2];
#pragma unroll
  for (int j = 0; j < 2; ++j) {
    int gg = wave * 2 + j;
    int slot = gg * 64 + lane;
    int qq = slot >> 7, m = slot & 127;
    gA[j] = A + (size_t)(rowBase + m) * KDIM + qq * 8;
    gB[j] = Bm + (size_t)(colBase + m) * KDIM + qq * 8;
    ldsOff[j] = (uint32_t)(gg * 64 * 8);  // wave-uniform LDS base (elements)
  }

  floatx4 acc[4][4];
#pragma unroll
  for (int i = 0; i < 4; ++i)
#pragma unroll
    for (int j = 0; j < 4; ++j) acc[i][j] = (floatx4){0.f, 0.f, 0.f, 0.f};

  const int q = lane >> 4, mr = lane & 15;
  const int kBeg = ks * KHALF, kEnd = kBeg + KHALF;

  // prologue: stage tiles 0,1,2 into buffers 0,1,2 (12 loads in flight)
#pragma unroll
  for (int t = 0; t < 3; ++t) {
    GLL(gA[0] + kBeg + t * 32, &lsA[t][0] + ldsOff[0]);
    GLL(gB[0] + kBeg + t * 32, &lsB[t][0] + ldsOff[0]);
    GLL(gA[1] + kBeg + t * 32, &lsA[t][0] + ldsOff[1]);
    GLL(gB[1] + kBeg + t * 32, &lsB[t][0] + ldsOff[1]);
  }

  // main: wait vmcnt(8) = drain current tile, keep 2 in flight
  for (int k0 = kBeg; k0 < kEnd - 64; k0 += 32) STEP(0xF78, k0);
  STEP(0xF74, kEnd - 64);  // vmcnt(4)
  STEP(0xF70, kEnd - 32);  // vmcnt(0)

  uint16_t* Dp = D + (size_t)ks * PSTRIDE;
  // epilogue: C/D layout col=lane&15, row=(lane>>4)*4+reg
#pragma unroll
  for (int rt = 0; rt < 4; ++rt) {
#pragma unroll
    for (int r = 0; r < 4; ++r) {
      int rowg = rowBase + wr * 64 + rt * 16 + (lane >> 4) * 4 + r;
      int b = rowg / CPB, c = rowg - b * CPB;
      int jj;
      if (MODE == 1) jj = (c < 2) ? (2 * s + c) : (4 + 16 * s + (c - 2));
      else jj = 16 * s + c;
      uint16_t* drow = Dp + (size_t)(b * OUTC + jj) * NNODE;
#pragma unroll
      for (int ct = 0; ct < 4; ++ct) {
        int colg = colBase + wc * 64 + ct * 16 + mr;
        drow[colg] = f2b(acc[rt][ct][r]);
      }
    }
  }
}

// ---------- stage2: r,u gates; X2 = r*prev (bf16), U kept fp32 ----------
__global__ __launch_bounds__(256) void stage2(
    const uint16_t* __restrict__ P1, const float* __restrict__ state,
    const float* __restrict__ rk, const float* __restrict__ uk,
    uint16_t* __restrict__ X2, float* __restrict__ U) {
  constexpr size_t PS = (size_t)64 * 36 * NNODE;
  __shared__ float s_rk[576], s_uk[576];
  for (int i = threadIdx.x; i < 576; i += 256) { s_rk[i] = rk[i]; s_uk[i] = uk[i]; }
  __syncthreads();
  int idx = blockIdx.x * 256 + threadIdx.x;
  int b = idx >> 12, n = idx & 4095;
  float hs[36];
  const uint16_t* p = P1 + (size_t)b * 36 * NNODE + n;
#pragma unroll
  for (int j = 0; j < 36; ++j)
    hs[j] = b2f(p[(size_t)j * NNODE]) + b2f(p[PS + (size_t)j * NNODE]);
  float ar[16], au[16];
#pragma unroll
  for (int k = 0; k < 16; ++k) { ar[k] = 0.f; au[k] = 0.f; }
#pragma unroll
  for (int j = 0; j < 36; ++j) {
    float h = hs[j];
#pragma unroll
    for (int k = 0; k < 16; ++k) {
      ar[k] += h * s_rk[j * 16 + k];
      au[k] += h * s_uk[j * 16 + k];
    }
  }
  const float* sp = state + (size_t)b * 65536 + n;
#pragma unroll
  for (int k = 0; k < 16; ++k) {
    float r = 1.f / (1.f + __expf(-ar[k]));
    float uu = 1.f / (1.f + __expf(-au[k]));
    float prev = sp[(size_t)k * NNODE];
    X2[(size_t)(b * 16 + k) * NNODE + n] = f2b(r * prev);
    U[(size_t)(b * 16 + k) * NNODE + n] = uu;
  }
}

// ---------- stage4: c = tanh([h;D3]*ck); z = u*prev + (1-u)*c ----------
// OUTPUT LAYOUT: z is (B, N, U) reshaped to (B, U*N) => out[b*65536 + n*16 + k]
__global__ __launch_bounds__(256) void stage4(
    const uint16_t* __restrict__ P1, const uint16_t* __restrict__ P3,
    const float* __restrict__ U, const float* __restrict__ state,
    const float* __restrict__ ck, float* __restrict__ out) {
  constexpr size_t PS1 = (size_t)64 * 36 * NNODE;
  constexpr size_t PS3 = (size_t)64 * 32 * NNODE;
  __shared__ float s_ck[576];
  for (int i = threadIdx.x; i < 576; i += 256) s_ck[i] = ck[i];
  __syncthreads();
  int idx = blockIdx.x * 256 + threadIdx.x;
  int b = idx >> 12, n = idx & 4095;
  float hv[36];
  const uint16_t* p1 = P1 + (size_t)b * 36 * NNODE + n;
#pragma unroll
  for (int j = 0; j < 4; ++j)
    hv[j] = b2f(p1[(size_t)j * NNODE]) + b2f(p1[PS1 + (size_t)j * NNODE]);
  const uint16_t* p3 = P3 + (size_t)b * 32 * NNODE + n;
#pragma unroll
  for (int j = 0; j < 32; ++j)
    hv[4 + j] = b2f(p3[(size_t)j * NNODE]) + b2f(p3[PS3 + (size_t)j * NNODE]);
  float ac[16];
#pragma unroll
  for (int k = 0; k < 16; ++k) ac[k] = 0.f;
#pragma unroll
  for (int j = 0; j < 36; ++j) {
    float h = hv[j];
#pragma unroll
    for (int k = 0; k < 16; ++k) ac[k] += h * s_ck[j * 16 + k];
  }
  const float* sp = state + (size_t)b * 65536 + n;
  const float* up = U + (size_t)b * 16 * NNODE + n;
  float z[16];
#pragma unroll
  for (int k = 0; k < 16; ++k) {
    float e = __expf(2.f * ac[k]);
    float c = 1.f - 2.f / (e + 1.f);  // tanh, saturates correctly at +/-inf
    float uu = up[(size_t)k * NNODE];
    float prev = sp[(size_t)k * NNODE];
    z[k] = uu * prev + (1.f - uu) * c;
  }
  float4* po = (float4*)(out + (size_t)b * 65536 + (size_t)n * 16);
#pragma unroll
  for (int k4 = 0; k4 < 4; ++k4)
    po[k4] = make_float4(z[k4 * 4], z[k4 * 4 + 1], z[k4 * 4 + 2], z[k4 * 4 + 3]);
}

extern "C" void kernel_launch(void* const* d_in, const int* in_sizes, int n_in,
                              void* d_out, int out_size, void* d_ws, size_t ws_size,
                              hipStream_t stream) {
  const float* inputs = (const float*)d_in[0];
  const float* state = (const float*)d_in[1];
  const float* s0 = (const float*)d_in[2];
  const float* s1 = (const float*)d_in[3];
  const float* rk = (const float*)d_in[4];
  const float* uk = (const float*)d_in[5];
  const float* ck = (const float*)d_in[6];
  float* out = (float*)d_out;
  char* ws = (char*)d_ws;

  // workspace layout (bytes); X2 aliases X1 (dead after gemm1)
  uint16_t* S0b = (uint16_t*)(ws);                  // 33,554,432
  uint16_t* S1b = (uint16_t*)(ws + 33554432);       // 33,554,432
  uint16_t* X1 = (uint16_t*)(ws + 67108864);        // 9,437,184   (1152 x 4096 bf16)
  uint16_t* X2 = (uint16_t*)(ws + 67108864);        // 8,388,608   (aliases X1)
  uint16_t* P1 = (uint16_t*)(ws + 76546048);        // 2 x 18,874,368 (split-K partials)
  float* U = (float*)(ws + 114294784);              // 16,777,216  (64 x 16 x 4096 f32)
  uint16_t* P3 = (uint16_t*)(ws + 131072000);       // 2 x 16,777,216 (split-K partials)
  // total 164,626,432 bytes

  cvt_supports<<<dim3(16384, 2), 256, 0, stream>>>(s0, s1, S0b, S1b);
  pack_x1<<<4608, 256, 0, stream>>>(inputs, state, X1);
  gemm_bt<1><<<1152, 256, 0, stream>>>(X1, S0b, S1b, P1);
  stage2<<<1024, 256, 0, stream>>>(P1, state, rk, uk, X2, U);
  gemm_bt<3><<<1024, 256, 0, stream>>>(X2, S0b, S1b, P3);
  stage4<<<1024, 256, 0, stream>>>(P1, P3, U, state, ck, out);
}

// Round 7
// 433.953 us; speedup vs baseline: 1.2180x; 1.2180x over previous
//
#include <hip/hip_runtime.h>
#include <cstdint>

#define KDIM 4096
#define NNODE 4096
#define KSPLIT 2
#define TSTEPS 128            // K-steps of 32 over KDIM
#define THALF (TSTEPS / KSPLIT)

typedef __bf16 bf16x8 __attribute__((ext_vector_type(8)));
typedef float floatx4 __attribute__((ext_vector_type(4)));

__device__ __forceinline__ uint16_t f2b(float f) {
  union { float f; uint32_t u; } v; v.f = f;
  uint32_t u = v.u;
  return (uint16_t)((u + 0x7FFFu + ((u >> 16) & 1u)) >> 16);  // RNE
}
__device__ __forceinline__ float b2f(uint16_t h) {
  union { uint32_t u; float f; } v; v.u = ((uint32_t)h) << 16; return v.f;
}
__device__ __forceinline__ uint32_t pack2(float a, float b) {
  return (uint32_t)f2b(a) | ((uint32_t)f2b(b) << 16);
}

// Fragment layout (both GEMM operands): frag[f16][t][lane][8] where
// elem = M[f16*16 + mr][t*32 + q*8 + j], lane = q*16 + mr.
// A wave's fragment load = base + lane*16B -> one fully-coalesced 1KB dwordx4.

// ---------- supports: fp32 row-major -> bf16 fragment layout ----------
__global__ __launch_bounds__(256) void cvt_supports(
    const float* __restrict__ s0, const float* __restrict__ s1,
    uint16_t* __restrict__ d0, uint16_t* __restrict__ d1) {
  const float* src = blockIdx.z ? s1 : s0;
  uint16_t* dst = blockIdx.z ? d1 : d0;
  const int c16 = blockIdx.x, kb = blockIdx.y;      // 256 x 32
  const int col_in = threadIdx.x >> 4, k8 = threadIdx.x & 15;
  const int col = c16 * 16 + col_in;
  const int k = kb * 128 + k8 * 8;
  const float* p = src + (size_t)col * KDIM + k;
  float4 v0 = *(const float4*)p;
  float4 v1 = *(const float4*)(p + 4);
  uint4 o;
  o.x = pack2(v0.x, v0.y); o.y = pack2(v0.z, v0.w);
  o.z = pack2(v1.x, v1.y); o.w = pack2(v1.z, v1.w);
  size_t off = ((size_t)(c16 * 128 + kb * 4 + (k8 >> 2))) * 512 +
               (size_t)((k8 & 3) * 16 + col_in) * 8;
  *(uint4*)(dst + off) = o;
}

// ---------- X1 (gemm1 A): rows (b,[feats(2);prev(16)]) -> fragment layout ----------
__global__ __launch_bounds__(256) void pack_x1(
    const float* __restrict__ inp, const float* __restrict__ st,
    uint16_t* __restrict__ X1) {
  const int r16 = blockIdx.x, kb = blockIdx.y;      // 72 x 32
  const int row_in = threadIdx.x >> 4, k8 = threadIdx.x & 15;
  const int row = r16 * 16 + row_in;
  const int k = kb * 128 + k8 * 8;
  int b = row / 18, c = row - b * 18;
  const float* p = (c < 2) ? (inp + (size_t)b * 8192 + (size_t)c * 4096 + k)
                           : (st + (size_t)b * 65536 + (size_t)(c - 2) * 4096 + k);
  float4 v0 = *(const float4*)p;
  float4 v1 = *(const float4*)(p + 4);
  uint4 o;
  o.x = pack2(v0.x, v0.y); o.y = pack2(v0.z, v0.w);
  o.z = pack2(v1.x, v1.y); o.w = pack2(v1.z, v1.w);
  size_t off = ((size_t)(r16 * 128 + kb * 4 + (k8 >> 2))) * 512 +
               (size_t)((k8 & 3) * 16 + row_in) * 8;
  *(uint4*)(X1 + off) = o;
}

// ---------- barrier-free register-streaming GEMM ----------
// C = A * S^T with both operands pre-packed in fragment layout. 128x128 tile,
// 4 waves (2x2), 16x16x32 MFMA, split-K=2. NO LDS, NO barriers: each wave
// streams its 8 fragments/step via coalesced 1KB dwordx4 loads, depth-4
// register pipeline (4 sets; compiler emits partial vmcnt waits). R6 showed
// the staging structure's barrier+drain — not load latency — was the wall.
template <int MODE>
__global__ __launch_bounds__(256) void gemm_frag(
    const uint16_t* __restrict__ Af, const uint16_t* __restrict__ S0f,
    const uint16_t* __restrict__ S1f, uint16_t* __restrict__ D) {
  constexpr int CPB = (MODE == 1) ? 18 : 16;
  constexpr int OUTC = (MODE == 1) ? 36 : 32;
  constexpr size_t PSTRIDE = (size_t)64 * OUTC * NNODE;
  const int lane = threadIdx.x & 63, wave = threadIdx.x >> 6;
  const int wr = wave >> 1, wc = wave & 1;
  const int s = blockIdx.z & 1, ks = blockIdx.z >> 1;
  const uint16_t* __restrict__ Bf = s ? S1f : S0f;
  const int yF = blockIdx.y * 8;   // row-frag base
  const int xF = blockIdx.x * 8;   // col-frag base

  const uint16_t* pA[4];
  const uint16_t* pB[4];
#pragma unroll
  for (int rt = 0; rt < 4; ++rt)
    pA[rt] = Af + (size_t)(yF + wr * 4 + rt) * 128 * 512 + (size_t)lane * 8;
#pragma unroll
  for (int ct = 0; ct < 4; ++ct)
    pB[ct] = Bf + (size_t)(xF + wc * 4 + ct) * 128 * 512 + (size_t)lane * 8;

  floatx4 acc[4][4];
#pragma unroll
  for (int i = 0; i < 4; ++i)
#pragma unroll
    for (int j = 0; j < 4; ++j) acc[i][j] = (floatx4){0.f, 0.f, 0.f, 0.f};

  const int tBeg = ks * THALF, tEnd = tBeg + THALF;

  bf16x8 a[4][4], bb[4][4];
  // prologue: preload 4 sets (t = tBeg .. tBeg+3)
#pragma unroll
  for (int u = 0; u < 4; ++u) {
#pragma unroll
    for (int rt = 0; rt < 4; ++rt)
      a[u][rt] = *(const bf16x8*)(pA[rt] + (size_t)(tBeg + u) * 512);
#pragma unroll
    for (int ct = 0; ct < 4; ++ct)
      bb[u][ct] = *(const bf16x8*)(pB[ct] + (size_t)(tBeg + u) * 512);
  }

  for (int tb = tBeg; tb < tEnd; tb += 4) {
#pragma unroll
    for (int u = 0; u < 4; ++u) {
#pragma unroll
      for (int rt = 0; rt < 4; ++rt)
#pragma unroll
        for (int ct = 0; ct < 4; ++ct)
          acc[rt][ct] = __builtin_amdgcn_mfma_f32_16x16x32_bf16(
              a[u][rt], bb[u][ct], acc[rt][ct], 0, 0, 0);
      int tl = tb + u + 4;
      if (tl > tEnd - 1) tl = tEnd - 1;  // clamped redundant tail loads
#pragma unroll
      for (int rt = 0; rt < 4; ++rt)
        a[u][rt] = *(const bf16x8*)(pA[rt] + (size_t)tl * 512);
#pragma unroll
      for (int ct = 0; ct < 4; ++ct)
        bb[u][ct] = *(const bf16x8*)(pB[ct] + (size_t)tl * 512);
    }
  }

  uint16_t* Dp = D + (size_t)ks * PSTRIDE;
  // epilogue: C/D layout col=lane&15, row=(lane>>4)*4+reg; D row-major bf16
#pragma unroll
  for (int rt = 0; rt < 4; ++rt) {
#pragma unroll
    for (int r = 0; r < 4; ++r) {
      int rowg = yF * 16 + wr * 64 + rt * 16 + (lane >> 4) * 4 + r;
      int b = rowg / CPB, c = rowg - b * CPB;
      int jj;
      if (MODE == 1) jj = (c < 2) ? (2 * s + c) : (4 + 16 * s + (c - 2));
      else jj = 16 * s + c;
      uint16_t* drow = Dp + (size_t)(b * OUTC + jj) * NNODE;
#pragma unroll
      for (int ct = 0; ct < 4; ++ct) {
        int colg = xF * 16 + wc * 64 + ct * 16 + (lane & 15);
        drow[colg] = f2b(acc[rt][ct][r]);
      }
    }
  }
}

// ---------- stage2: r,u gates; X2 = r*prev -> fragment layout via LDS transpose ----------
__global__ __launch_bounds__(256) void stage2(
    const uint16_t* __restrict__ P1, const float* __restrict__ state,
    const float* __restrict__ rk, const float* __restrict__ uk,
    uint16_t* __restrict__ X2f, float* __restrict__ U) {
  constexpr size_t PS = (size_t)64 * 36 * NNODE;
  __shared__ float s_rk[576], s_uk[576];
  __shared__ uint16_t s_x2[16 * 264];  // [k][i], padded stride (264) vs 256
  for (int i = threadIdx.x; i < 576; i += 256) { s_rk[i] = rk[i]; s_uk[i] = uk[i]; }
  __syncthreads();
  const int b = blockIdx.x >> 4, nb = blockIdx.x & 15;
  const int i = threadIdx.x;
  const int n = nb * 256 + i;
  float hs[36];
  const uint16_t* p = P1 + (size_t)b * 36 * NNODE + n;
#pragma unroll
  for (int j = 0; j < 36; ++j)
    hs[j] = b2f(p[(size_t)j * NNODE]) + b2f(p[PS + (size_t)j * NNODE]);
  float ar[16], au[16];
#pragma unroll
  for (int k = 0; k < 16; ++k) { ar[k] = 0.f; au[k] = 0.f; }
#pragma unroll
  for (int j = 0; j < 36; ++j) {
    float h = hs[j];
#pragma unroll
    for (int k = 0; k < 16; ++k) {
      ar[k] += h * s_rk[j * 16 + k];
      au[k] += h * s_uk[j * 16 + k];
    }
  }
  const float* sp = state + (size_t)b * 65536 + n;
#pragma unroll
  for (int k = 0; k < 16; ++k) {
    float r = 1.f / (1.f + __expf(-ar[k]));
    float uu = 1.f / (1.f + __expf(-au[k]));
    float prev = sp[(size_t)k * NNODE];
    s_x2[k * 264 + i] = f2b(r * prev);
    U[(size_t)(b * 16 + k) * NNODE + n] = uu;
  }
  __syncthreads();
  // flush 4096 bf16 (16 k x 256 n) to fragment layout: contiguous 8KB region.
  // global o = tl*512 + (qq*16+kk)*8 + jj ; element = (row b*16+kk, n nb*256 + tl*32+qq*8+jj)
  uint16_t* region = X2f + ((size_t)b * 128 + nb * 8) * 512;
#pragma unroll
  for (int rr = 0; rr < 2; ++rr) {
    int fid = rr * 256 + i;
    int kk = fid & 15, qq = (fid >> 4) & 3, tl = fid >> 6;
    uint4 v = *(const uint4*)&s_x2[kk * 264 + tl * 32 + qq * 8];
    *(uint4*)(region + (size_t)fid * 8) = v;
  }
}

// ---------- stage4: c = tanh([h;D3]*ck); z = u*prev + (1-u)*c ----------
// OUTPUT LAYOUT: z is (B, N, U) reshaped -> out[b*65536 + n*16 + k]
__global__ __launch_bounds__(256) void stage4(
    const uint16_t* __restrict__ P1, const uint16_t* __restrict__ P3,
    const float* __restrict__ U, const float* __restrict__ state,
    const float* __restrict__ ck, float* __restrict__ out) {
  constexpr size_t PS1 = (size_t)64 * 36 * NNODE;
  constexpr size_t PS3 = (size_t)64 * 32 * NNODE;
  __shared__ float s_ck[576];
  for (int i = threadIdx.x; i < 576; i += 256) s_ck[i] = ck[i];
  __syncthreads();
  int idx = blockIdx.x * 256 + threadIdx.x;
  int b = idx >> 12, n = idx & 4095;
  float hv[36];
  const uint16_t* p1 = P1 + (size_t)b * 36 * NNODE + n;
#pragma unroll
  for (int j = 0; j < 4; ++j)
    hv[j] = b2f(p1[(size_t)j * NNODE]) + b2f(p1[PS1 + (size_t)j * NNODE]);
  const uint16_t* p3 = P3 + (size_t)b * 32 * NNODE + n;
#pragma unroll
  for (int j = 0; j < 32; ++j)
    hv[4 + j] = b2f(p3[(size_t)j * NNODE]) + b2f(p3[PS3 + (size_t)j * NNODE]);
  float ac[16];
#pragma unroll
  for (int k = 0; k < 16; ++k) ac[k] = 0.f;
#pragma unroll
  for (int j = 0; j < 36; ++j) {
    float h = hv[j];
#pragma unroll
    for (int k = 0; k < 16; ++k) ac[k] += h * s_ck[j * 16 + k];
  }
  const float* sp = state + (size_t)b * 65536 + n;
  const float* up = U + (size_t)b * 16 * NNODE + n;
  float z[16];
#pragma unroll
  for (int k = 0; k < 16; ++k) {
    float e = __expf(2.f * ac[k]);
    float c = 1.f - 2.f / (e + 1.f);  // tanh, saturates at +/-inf
    float uu = up[(size_t)k * NNODE];
    float prev = sp[(size_t)k * NNODE];
    z[k] = uu * prev + (1.f - uu) * c;
  }
  float4* po = (float4*)(out + (size_t)b * 65536 + (size_t)n * 16);
#pragma unroll
  for (int k4 = 0; k4 < 4; ++k4)
    po[k4] = make_float4(z[k4 * 4], z[k4 * 4 + 1], z[k4 * 4 + 2], z[k4 * 4 + 3]);
}

extern "C" void kernel_launch(void* const* d_in, const int* in_sizes, int n_in,
                              void* d_out, int out_size, void* d_ws, size_t ws_size,
                              hipStream_t stream) {
  const float* inputs = (const float*)d_in[0];
  const float* state = (const float*)d_in[1];
  const float* s0 = (const float*)d_in[2];
  const float* s1 = (const float*)d_in[3];
  const float* rk = (const float*)d_in[4];
  const float* uk = (const float*)d_in[5];
  const float* ck = (const float*)d_in[6];
  float* out = (float*)d_out;
  char* ws = (char*)d_ws;

  // workspace layout (bytes); X2f aliases X1f (dead after gemm1)
  uint16_t* S0f = (uint16_t*)(ws);                  // 33,554,432
  uint16_t* S1f = (uint16_t*)(ws + 33554432);       // 33,554,432
  uint16_t* X1f = (uint16_t*)(ws + 67108864);       // 9,437,184   (1152 x 4096 bf16, frag)
  uint16_t* X2f = (uint16_t*)(ws + 67108864);       // 8,388,608   (aliases X1f, frag)
  uint16_t* P1 = (uint16_t*)(ws + 76546048);        // 2 x 18,874,368 (split-K partials)
  float* U = (float*)(ws + 114294784);              // 16,777,216
  uint16_t* P3 = (uint16_t*)(ws + 131072000);       // 2 x 16,777,216 (split-K partials)
  // total 164,626,432 bytes

  cvt_supports<<<dim3(256, 32, 2), 256, 0, stream>>>(s0, s1, S0f, S1f);
  pack_x1<<<dim3(72, 32), 256, 0, stream>>>(inputs, state, X1f);
  gemm_frag<1><<<dim3(32, 9, 2 * KSPLIT), 256, 0, stream>>>(X1f, S0f, S1f, P1);
  stage2<<<1024, 256, 0, stream>>>(P1, state, rk, uk, X2f, U);
  gemm_frag<3><<<dim3(32, 8, 2 * KSPLIT), 256, 0, stream>>>(X2f, S0f, S1f, P3);
  stage4<<<1024, 256, 0, stream>>>(P1, P3, U, state, ck, out);
}